// Round 1
// baseline (364.503 us; speedup 1.0000x reference)
//
#include <hip/hip_runtime.h>
#include <hip/hip_bf16.h>
#include <math.h>

#define TOK_PER_BLK 4
#define THREADS 256
#define CHUNK 6     // weight rows per register chunk
#define NCHUNK 4    // 24 rows total
#define NROWS 24
#define TAU_INV 20.0f   // 1/0.05

// One block = 4 tokens. Each token is a 4096-float vector (S=4 streams x D=1024).
__global__ __launch_bounds__(THREADS, 2)
void hc_fused(const float* __restrict__ resid,
              const float* __restrict__ gamma,
              const float* __restrict__ w_res,
              const float* __restrict__ w_pre,
              const float* __restrict__ w_post,
              const float* __restrict__ beta_res,
              const float* __restrict__ beta_pre,
              const float* __restrict__ beta_post,
              const float* __restrict__ p_alpha_res,
              const float* __restrict__ p_alpha_pre,
              const float* __restrict__ p_alpha_post,
              float* __restrict__ out)
{
    __shared__ float4 sh_h[TOK_PER_BLK][1024];          // 64 KB token data
    __shared__ float  sh_ssq[4][TOK_PER_BLK];           // per-wave sumsq partials
    __shared__ float  sh_wpart[4][TOK_PER_BLK][NROWS];  // per-wave dot partials
    __shared__ float  sh_raw[TOK_PER_BLK][NROWS];       // final raw dots
    __shared__ float  sh_H[TOK_PER_BLK][NROWS];         // [0..15]=H_res, [16..19]=H_pre, [20..23]=H_post

    const int tid  = threadIdx.x;
    const int wave = tid >> 6;
    const int lane = tid & 63;
    const long tok0 = (long)blockIdx.x * TOK_PER_BLK;

    // ---------------- Phase 1: global -> LDS + sumsq ----------------
    const float4* hp = (const float4*)resid + tok0 * 1024;
    float ssq[TOK_PER_BLK];
    #pragma unroll
    for (int m = 0; m < TOK_PER_BLK; ++m) {
        float s = 0.f;
        #pragma unroll
        for (int k = 0; k < 4; ++k) {
            float4 v = hp[m * 1024 + k * 256 + tid];
            sh_h[m][k * 256 + tid] = v;
            s += v.x * v.x + v.y * v.y + v.z * v.z + v.w * v.w;
        }
        ssq[m] = s;
    }
    #pragma unroll
    for (int m = 0; m < TOK_PER_BLK; ++m) {
        float s = ssq[m];
        #pragma unroll
        for (int off = 1; off < 64; off <<= 1)
            s += __shfl_xor(s, off, 64);
        if (lane == 0) sh_ssq[wave][m] = s;
    }

    // gamma+1 in registers: thread owns float4 indices {tid + q*256}
    float4 g[4];
    {
        const float4* gp = (const float4*)gamma;
        #pragma unroll
        for (int q = 0; q < 4; ++q) {
            float4 gv = gp[q * 256 + tid];
            g[q] = make_float4(gv.x + 1.f, gv.y + 1.f, gv.z + 1.f, gv.w + 1.f);
        }
    }
    __syncthreads();

    // ---------------- Phase 2: 24 dot products (chunked weights in regs) ----
    #pragma unroll 1
    for (int c = 0; c < NCHUNK; ++c) {
        float4 w[CHUNK][4];
        #pragma unroll
        for (int r = 0; r < CHUNK; ++r) {
            const int e = c * CHUNK + r;
            const float* wr = (e < 16) ? (w_res + (size_t)e * 4096)
                            : (e < 20) ? (w_pre + (size_t)(e - 16) * 4096)
                                       : (w_post + (size_t)(e - 20) * 4096);
            const float4* wr4 = (const float4*)wr;
            #pragma unroll
            for (int q = 0; q < 4; ++q) w[r][q] = wr4[q * 256 + tid];
        }
        float acc[CHUNK][TOK_PER_BLK];
        #pragma unroll
        for (int m = 0; m < TOK_PER_BLK; ++m) {
            float4 p[4];
            #pragma unroll
            for (int q = 0; q < 4; ++q) {
                float4 t = sh_h[m][q * 256 + tid];
                p[q] = make_float4(t.x * g[q].x, t.y * g[q].y, t.z * g[q].z, t.w * g[q].w);
            }
            #pragma unroll
            for (int r = 0; r < CHUNK; ++r) {
                float a = 0.f;
                #pragma unroll
                for (int q = 0; q < 4; ++q)
                    a += w[r][q].x * p[q].x + w[r][q].y * p[q].y
                       + w[r][q].z * p[q].z + w[r][q].w * p[q].w;
                acc[r][m] = a;
            }
        }
        #pragma unroll
        for (int r = 0; r < CHUNK; ++r) {
            #pragma unroll
            for (int m = 0; m < TOK_PER_BLK; ++m) {
                float a = acc[r][m];
                #pragma unroll
                for (int off = 1; off < 64; off <<= 1)
                    a += __shfl_xor(a, off, 64);
                if (lane == 0) sh_wpart[wave][m][c * CHUNK + r] = a;
            }
        }
    }
    __syncthreads();
    if (tid < NROWS * TOK_PER_BLK) {
        const int e = tid % NROWS, m = tid / NROWS;
        sh_raw[m][e] = sh_wpart[0][m][e] + sh_wpart[1][m][e]
                     + sh_wpart[2][m][e] + sh_wpart[3][m][e];
    }
    __syncthreads();

    // ---------------- Phase 3: sinkhorn + gates (one wave per token) --------
    {
        const int m   = wave;          // TOK_PER_BLK == number of waves
        const int idx = lane & 15;     // (i,j): i = idx>>2, j = idx&3
        const int jj  = idx & 3;

        float ss  = sh_ssq[0][m] + sh_ssq[1][m] + sh_ssq[2][m] + sh_ssq[3][m];
        float scale = 64.0f / fmaxf(sqrtf(ss), 1e-12f);

        const float a_res  = p_alpha_res[0];
        const float a_pre  = p_alpha_pre[0];
        const float a_post = p_alpha_post[0];

        float Z = (beta_res[idx] + a_res * scale * sh_raw[m][idx]) * TAU_INV;
        float u = 0.f, v = 0.f;
        #pragma unroll 1
        for (int it = 0; it < 10; ++it) {
            // u_i = -logsumexp_j(Z_ij + v_j)   (j = lane bits 0,1)
            float t  = Z + v;
            float mx = t;
            mx = fmaxf(mx, __shfl_xor(mx, 1, 64));
            mx = fmaxf(mx, __shfl_xor(mx, 2, 64));
            float sm = __expf(t - mx);
            sm += __shfl_xor(sm, 1, 64);
            sm += __shfl_xor(sm, 2, 64);
            u = -(mx + __logf(sm));
            // v_j = -logsumexp_i(Z_ij + u_i)   (i = lane bits 2,3)
            t  = Z + u;
            mx = t;
            mx = fmaxf(mx, __shfl_xor(mx, 4, 64));
            mx = fmaxf(mx, __shfl_xor(mx, 8, 64));
            sm = __expf(t - mx);
            sm += __shfl_xor(sm, 4, 64);
            sm += __shfl_xor(sm, 8, 64);
            v = -(mx + __logf(sm));
        }
        float P = __expf(Z + u + v);
        if (lane < 16) sh_H[m][idx] = P;

        // H_pre: softmax over s (use lanes' j as s; groups of 4 lanes)
        float lpre = beta_pre[jj] + a_pre * scale * sh_raw[m][16 + jj];
        float mxp = lpre;
        mxp = fmaxf(mxp, __shfl_xor(mxp, 1, 64));
        mxp = fmaxf(mxp, __shfl_xor(mxp, 2, 64));
        float ep = __expf(lpre - mxp);
        float sp = ep;
        sp += __shfl_xor(sp, 1, 64);
        sp += __shfl_xor(sp, 2, 64);
        float hpre = ep / sp;
        // H_post: 2*sigmoid
        float lpost = beta_post[jj] + a_post * scale * sh_raw[m][20 + jj];
        float hpost = 2.0f / (1.0f + __expf(-lpost));
        if (lane < 4) { sh_H[m][16 + jj] = hpre; sh_H[m][20 + jj] = hpost; }
    }
    __syncthreads();

    // ---------------- Phase 4: remix + branch, store -------------------------
    #pragma unroll 1
    for (int m = 0; m < TOK_PER_BLK; ++m) {
        float4 hs[4];
        #pragma unroll
        for (int s = 0; s < 4; ++s) hs[s] = sh_h[m][s * 256 + tid];
        float Hr[16], Hp[4], Ho[4];
        #pragma unroll
        for (int k = 0; k < 16; ++k) Hr[k] = sh_H[m][k];
        #pragma unroll
        for (int s = 0; s < 4; ++s) { Hp[s] = sh_H[m][16 + s]; Ho[s] = sh_H[m][20 + s]; }

        float4 br;
        br.x = Hp[0]*hs[0].x + Hp[1]*hs[1].x + Hp[2]*hs[2].x + Hp[3]*hs[3].x;
        br.y = Hp[0]*hs[0].y + Hp[1]*hs[1].y + Hp[2]*hs[2].y + Hp[3]*hs[3].y;
        br.z = Hp[0]*hs[0].z + Hp[1]*hs[1].z + Hp[2]*hs[2].z + Hp[3]*hs[3].z;
        br.w = Hp[0]*hs[0].w + Hp[1]*hs[1].w + Hp[2]*hs[2].w + Hp[3]*hs[3].w;

        float4* op = (float4*)out + (tok0 + m) * 1024;
        #pragma unroll
        for (int i = 0; i < 4; ++i) {
            float4 o;
            o.x = Hr[i*4+0]*hs[0].x + Hr[i*4+1]*hs[1].x + Hr[i*4+2]*hs[2].x + Hr[i*4+3]*hs[3].x + Ho[i]*br.x;
            o.y = Hr[i*4+0]*hs[0].y + Hr[i*4+1]*hs[1].y + Hr[i*4+2]*hs[2].y + Hr[i*4+3]*hs[3].y + Ho[i]*br.y;
            o.z = Hr[i*4+0]*hs[0].z + Hr[i*4+1]*hs[1].z + Hr[i*4+2]*hs[2].z + Hr[i*4+3]*hs[3].z + Ho[i]*br.z;
            o.w = Hr[i*4+0]*hs[0].w + Hr[i*4+1]*hs[1].w + Hr[i*4+2]*hs[2].w + Hr[i*4+3]*hs[3].w + Ho[i]*br.w;
            op[i * 256 + tid] = o;
        }
    }
}

extern "C" void kernel_launch(void* const* d_in, const int* in_sizes, int n_in,
                              void* d_out, int out_size, void* d_ws, size_t ws_size,
                              hipStream_t stream) {
    const float* resid      = (const float*)d_in[0];
    const float* gamma      = (const float*)d_in[1];
    const float* w_res      = (const float*)d_in[2];
    const float* w_pre      = (const float*)d_in[3];
    const float* w_post     = (const float*)d_in[4];
    const float* beta_res   = (const float*)d_in[5];
    const float* beta_pre   = (const float*)d_in[6];
    const float* beta_post  = (const float*)d_in[7];
    const float* alpha_res  = (const float*)d_in[8];
    const float* alpha_pre  = (const float*)d_in[9];
    const float* alpha_post = (const float*)d_in[10];
    float* out = (float*)d_out;

    const int ntok = in_sizes[0] / 4096;          // B*T = 8192
    const int grid = ntok / TOK_PER_BLK;          // 2048

    hc_fused<<<grid, THREADS, 0, stream>>>(resid, gamma, w_res, w_pre, w_post,
                                           beta_res, beta_pre, beta_post,
                                           alpha_res, alpha_pre, alpha_post, out);
}

// Round 2
// 351.208 us; speedup vs baseline: 1.0379x; 1.0379x over previous
//
#include <hip/hip_runtime.h>
#include <hip/hip_bf16.h>
#include <math.h>

#define TOK_PER_BLK 4
#define THREADS 256
#define CHUNK 2      // weight rows per register chunk
#define NCHUNK 12    // 24 rows total
#define NROWS 24
#define PCOL 68      // 64 partials + pad (16B-aligned, breaks bank alias)
#define TAU_INV 20.0f   // 1/0.05

// One block = 4 tokens, 256 threads. Token = 4096 floats (S=4 streams x D=1024).
// Thread tid holds float4 (q*256+tid) of each token in REGISTERS (q = stream).
__global__ __launch_bounds__(THREADS, 3)
void hc_fused(const float* __restrict__ resid,
              const float* __restrict__ gamma,
              const float* __restrict__ w_res,
              const float* __restrict__ w_pre,
              const float* __restrict__ w_post,
              const float* __restrict__ beta_res,
              const float* __restrict__ beta_pre,
              const float* __restrict__ beta_post,
              const float* __restrict__ p_alpha_res,
              const float* __restrict__ p_alpha_pre,
              const float* __restrict__ p_alpha_post,
              float* __restrict__ out)
{
    __shared__ float sh_part[NROWS * TOK_PER_BLK][PCOL];  // 26 KB dot partials
    __shared__ float sh_ssqp[TOK_PER_BLK][PCOL];          // sumsq partials
    __shared__ float sh_raw[TOK_PER_BLK][NROWS];
    __shared__ float sh_ssq[TOK_PER_BLK];
    __shared__ float sh_H[TOK_PER_BLK][NROWS];  // [0..15]=H_res, [16..19]=H_pre, [20..23]=H_post

    const int tid  = threadIdx.x;
    const int wave = tid >> 6;
    const int lane = tid & 63;
    const long tok0 = (long)blockIdx.x * TOK_PER_BLK;

    // ---------------- Phase 1: global -> registers + sumsq ----------------
    const float4* hp = (const float4*)resid + tok0 * 1024;
    float4 p[TOK_PER_BLK][4];
    #pragma unroll
    for (int m = 0; m < TOK_PER_BLK; ++m) {
        #pragma unroll
        for (int q = 0; q < 4; ++q)
            p[m][q] = hp[m * 1024 + q * 256 + tid];
    }
    #pragma unroll
    for (int m = 0; m < TOK_PER_BLK; ++m) {
        float s = 0.f;
        #pragma unroll
        for (int q = 0; q < 4; ++q) {
            float4 v = p[m][q];
            s += v.x * v.x + v.y * v.y + v.z * v.z + v.w * v.w;
        }
        s += __shfl_xor(s, 16, 64);
        s += __shfl_xor(s, 32, 64);
        if (lane < 16) sh_ssqp[m][wave * 16 + lane] = s;
    }

    // gamma+1 in registers
    float4 g[4];
    {
        const float4* gp = (const float4*)gamma;
        #pragma unroll
        for (int q = 0; q < 4; ++q) {
            float4 gv = gp[q * 256 + tid];
            g[q] = make_float4(gv.x + 1.f, gv.y + 1.f, gv.z + 1.f, gv.w + 1.f);
        }
    }

    // ---------------- Phase 2: 24 dot products ----------------
    // dot(w, x*(g+1)) = dot(w*(g+1), x): fold gamma into weights (1x per row,
    // reused over 4 tokens). rms scale applied in phase 3.
    #pragma unroll 1
    for (int c = 0; c < NCHUNK; ++c) {
        float4 wg[CHUNK][4];
        #pragma unroll
        for (int r = 0; r < CHUNK; ++r) {
            const int e = c * CHUNK + r;
            const float* wr = (e < 16) ? (w_res + (size_t)e * 4096)
                            : (e < 20) ? (w_pre + (size_t)(e - 16) * 4096)
                                       : (w_post + (size_t)(e - 20) * 4096);
            const float4* wr4 = (const float4*)wr;
            #pragma unroll
            for (int q = 0; q < 4; ++q) {
                float4 wv = wr4[q * 256 + tid];
                wg[r][q] = make_float4(wv.x * g[q].x, wv.y * g[q].y,
                                       wv.z * g[q].z, wv.w * g[q].w);
            }
        }
        float acc[CHUNK][TOK_PER_BLK];
        #pragma unroll
        for (int m = 0; m < TOK_PER_BLK; ++m) {
            #pragma unroll
            for (int r = 0; r < CHUNK; ++r) {
                float a = 0.f;
                #pragma unroll
                for (int q = 0; q < 4; ++q)
                    a += wg[r][q].x * p[m][q].x + wg[r][q].y * p[m][q].y
                       + wg[r][q].z * p[m][q].z + wg[r][q].w * p[m][q].w;
                acc[r][m] = a;
            }
        }
        // 2-step butterfly -> 16 partials per wave -> LDS
        #pragma unroll
        for (int r = 0; r < CHUNK; ++r) {
            #pragma unroll
            for (int m = 0; m < TOK_PER_BLK; ++m) {
                float a = acc[r][m];
                a += __shfl_xor(a, 16, 64);
                a += __shfl_xor(a, 32, 64);
                if (lane < 16)
                    sh_part[(c * CHUNK + r) * TOK_PER_BLK + m][wave * 16 + lane] = a;
            }
        }
    }
    __syncthreads();

    // ---------------- Reduce: parallel column sums ----------------
    if (tid < NROWS * TOK_PER_BLK) {           // 96 threads: one (row,token) each
        const int e = tid >> 2, m = tid & 3;
        const float4* src = (const float4*)&sh_part[e * TOK_PER_BLK + m][0];
        float4 s4 = src[0];
        #pragma unroll
        for (int j = 1; j < 16; ++j) {
            float4 v = src[j];
            s4.x += v.x; s4.y += v.y; s4.z += v.z; s4.w += v.w;
        }
        sh_raw[m][e] = s4.x + s4.y + s4.z + s4.w;
    } else if (tid < NROWS * TOK_PER_BLK + TOK_PER_BLK) {
        const int m = tid - NROWS * TOK_PER_BLK;
        const float4* src = (const float4*)&sh_ssqp[m][0];
        float4 s4 = src[0];
        #pragma unroll
        for (int j = 1; j < 16; ++j) {
            float4 v = src[j];
            s4.x += v.x; s4.y += v.y; s4.z += v.z; s4.w += v.w;
        }
        sh_ssq[m] = s4.x + s4.y + s4.z + s4.w;
    }
    __syncthreads();

    // ---------------- Phase 3: sinkhorn + gates (one wave per token) --------
    {
        const int m   = wave;
        const int idx = lane & 15;     // (i,j): i = idx>>2, j = idx&3
        const int jj  = idx & 3;

        float ss    = sh_ssq[m];
        float scale = 64.0f / fmaxf(sqrtf(ss), 1e-12f);

        const float a_res  = p_alpha_res[0];
        const float a_pre  = p_alpha_pre[0];
        const float a_post = p_alpha_post[0];

        float Z = (beta_res[idx] + a_res * scale * sh_raw[m][idx]) * TAU_INV;
        float u = 0.f, v = 0.f;
        #pragma unroll 1
        for (int it = 0; it < 10; ++it) {
            float t  = Z + v;
            float mx = t;
            mx = fmaxf(mx, __shfl_xor(mx, 1, 64));
            mx = fmaxf(mx, __shfl_xor(mx, 2, 64));
            float sm = __expf(t - mx);
            sm += __shfl_xor(sm, 1, 64);
            sm += __shfl_xor(sm, 2, 64);
            u = -(mx + __logf(sm));
            t  = Z + u;
            mx = t;
            mx = fmaxf(mx, __shfl_xor(mx, 4, 64));
            mx = fmaxf(mx, __shfl_xor(mx, 8, 64));
            sm = __expf(t - mx);
            sm += __shfl_xor(sm, 4, 64);
            sm += __shfl_xor(sm, 8, 64);
            v = -(mx + __logf(sm));
        }
        float P = __expf(Z + u + v);
        if (lane < 16) sh_H[m][idx] = P;

        float lpre = beta_pre[jj] + a_pre * scale * sh_raw[m][16 + jj];
        float mxp = lpre;
        mxp = fmaxf(mxp, __shfl_xor(mxp, 1, 64));
        mxp = fmaxf(mxp, __shfl_xor(mxp, 2, 64));
        float ep = __expf(lpre - mxp);
        float sp = ep;
        sp += __shfl_xor(sp, 1, 64);
        sp += __shfl_xor(sp, 2, 64);
        float hpre = ep / sp;
        float lpost = beta_post[jj] + a_post * scale * sh_raw[m][20 + jj];
        float hpost = 2.0f / (1.0f + __expf(-lpost));
        if (lane < 4) { sh_H[m][16 + jj] = hpre; sh_H[m][20 + jj] = hpost; }
    }
    __syncthreads();

    // ---------------- Phase 4: remix + branch, store (data from registers) --
    #pragma unroll 1
    for (int m = 0; m < TOK_PER_BLK; ++m) {
        float Hr[16], Hp[4], Ho[4];
        #pragma unroll
        for (int k = 0; k < 16; ++k) Hr[k] = sh_H[m][k];
        #pragma unroll
        for (int s = 0; s < 4; ++s) { Hp[s] = sh_H[m][16 + s]; Ho[s] = sh_H[m][20 + s]; }

        float4 br;
        br.x = Hp[0]*p[m][0].x + Hp[1]*p[m][1].x + Hp[2]*p[m][2].x + Hp[3]*p[m][3].x;
        br.y = Hp[0]*p[m][0].y + Hp[1]*p[m][1].y + Hp[2]*p[m][2].y + Hp[3]*p[m][3].y;
        br.z = Hp[0]*p[m][0].z + Hp[1]*p[m][1].z + Hp[2]*p[m][2].z + Hp[3]*p[m][3].z;
        br.w = Hp[0]*p[m][0].w + Hp[1]*p[m][1].w + Hp[2]*p[m][2].w + Hp[3]*p[m][3].w;

        float4* op = (float4*)out + (tok0 + m) * 1024;
        #pragma unroll
        for (int i = 0; i < 4; ++i) {
            float4 o;
            o.x = Hr[i*4+0]*p[m][0].x + Hr[i*4+1]*p[m][1].x + Hr[i*4+2]*p[m][2].x + Hr[i*4+3]*p[m][3].x + Ho[i]*br.x;
            o.y = Hr[i*4+0]*p[m][0].y + Hr[i*4+1]*p[m][1].y + Hr[i*4+2]*p[m][2].y + Hr[i*4+3]*p[m][3].y + Ho[i]*br.y;
            o.z = Hr[i*4+0]*p[m][0].z + Hr[i*4+1]*p[m][1].z + Hr[i*4+2]*p[m][2].z + Hr[i*4+3]*p[m][3].z + Ho[i]*br.z;
            o.w = Hr[i*4+0]*p[m][0].w + Hr[i*4+1]*p[m][1].w + Hr[i*4+2]*p[m][2].w + Hr[i*4+3]*p[m][3].w + Ho[i]*br.w;
            op[i * 256 + tid] = o;
        }
    }
}

extern "C" void kernel_launch(void* const* d_in, const int* in_sizes, int n_in,
                              void* d_out, int out_size, void* d_ws, size_t ws_size,
                              hipStream_t stream) {
    const float* resid      = (const float*)d_in[0];
    const float* gamma      = (const float*)d_in[1];
    const float* w_res      = (const float*)d_in[2];
    const float* w_pre      = (const float*)d_in[3];
    const float* w_post     = (const float*)d_in[4];
    const float* beta_res   = (const float*)d_in[5];
    const float* beta_pre   = (const float*)d_in[6];
    const float* beta_post  = (const float*)d_in[7];
    const float* alpha_res  = (const float*)d_in[8];
    const float* alpha_pre  = (const float*)d_in[9];
    const float* alpha_post = (const float*)d_in[10];
    float* out = (float*)d_out;

    const int ntok = in_sizes[0] / 4096;          // B*T = 8192
    const int grid = ntok / TOK_PER_BLK;          // 2048

    hc_fused<<<grid, THREADS, 0, stream>>>(resid, gamma, w_res, w_pre, w_post,
                                           beta_res, beta_pre, beta_post,
                                           alpha_res, alpha_pre, alpha_post, out);
}

// Round 3
// 307.945 us; speedup vs baseline: 1.1837x; 1.1405x over previous
//
#include <hip/hip_runtime.h>
#include <hip/hip_bf16.h>
#include <math.h>

#define TOK_PER_BLK 4
#define THREADS 256
#define CHUNK 2      // weight rows per register chunk
#define NCHUNK 12    // 24 rows total
#define NROWS 24
#define PCOL 68      // 64 partials + pad
#define TAU_INV 20.0f   // 1/0.05

// One block = 4 tokens, 256 threads. Token = 4096 floats (S=4 streams x D=1024).
// Thread tid holds float4 (q*256+tid) of each token in REGISTERS (q = stream).
// NOTE: every loop touching p[][] must be fully unrolled (compile-time indices)
// or the array spills to scratch — R2 showed +131MB WRITE_SIZE from exactly that.
__global__ __launch_bounds__(THREADS, 3)
void hc_fused(const float* __restrict__ resid,
              const float* __restrict__ gamma,
              const float* __restrict__ w_res,
              const float* __restrict__ w_pre,
              const float* __restrict__ w_post,
              const float* __restrict__ beta_res,
              const float* __restrict__ beta_pre,
              const float* __restrict__ beta_post,
              const float* __restrict__ p_alpha_res,
              const float* __restrict__ p_alpha_pre,
              const float* __restrict__ p_alpha_post,
              float* __restrict__ out)
{
    __shared__ float sh_part[NROWS * TOK_PER_BLK][PCOL];  // 26 KB dot partials
    __shared__ float sh_ssqp[TOK_PER_BLK][PCOL];          // sumsq partials
    __shared__ float sh_raw[TOK_PER_BLK][NROWS];
    __shared__ float sh_ssq[TOK_PER_BLK];
    __shared__ float sh_H[TOK_PER_BLK][NROWS];  // [0..15]=H_res, [16..19]=H_pre, [20..23]=H_post

    const int tid  = threadIdx.x;
    const int wave = tid >> 6;
    const int lane = tid & 63;
    const long tok0 = (long)blockIdx.x * TOK_PER_BLK;

    // ---------------- Phase 1: global -> registers + sumsq ----------------
    const float4* hp = (const float4*)resid + tok0 * 1024;
    float4 p[TOK_PER_BLK][4];
    #pragma unroll
    for (int m = 0; m < TOK_PER_BLK; ++m) {
        #pragma unroll
        for (int q = 0; q < 4; ++q)
            p[m][q] = hp[m * 1024 + q * 256 + tid];
    }
    #pragma unroll
    for (int m = 0; m < TOK_PER_BLK; ++m) {
        float s = 0.f;
        #pragma unroll
        for (int q = 0; q < 4; ++q) {
            float4 v = p[m][q];
            s += v.x * v.x + v.y * v.y + v.z * v.z + v.w * v.w;
        }
        s += __shfl_xor(s, 16, 64);
        s += __shfl_xor(s, 32, 64);
        if (lane < 16) sh_ssqp[m][wave * 16 + lane] = s;
    }

    // gamma+1 in registers
    float4 g[4];
    {
        const float4* gp = (const float4*)gamma;
        #pragma unroll
        for (int q = 0; q < 4; ++q) {
            float4 gv = gp[q * 256 + tid];
            g[q] = make_float4(gv.x + 1.f, gv.y + 1.f, gv.z + 1.f, gv.w + 1.f);
        }
    }

    // ---------------- Phase 2: 24 dot products ----------------
    // dot(w, x*(g+1)) = dot(w*(g+1), x): fold gamma into weights (1x per row,
    // reused over 4 tokens). rms scale applied in phase 3.
    #pragma unroll 1
    for (int c = 0; c < NCHUNK; ++c) {
        float4 wg[CHUNK][4];
        #pragma unroll
        for (int r = 0; r < CHUNK; ++r) {
            const int e = c * CHUNK + r;
            const float* wr = (e < 16) ? (w_res + (size_t)e * 4096)
                            : (e < 20) ? (w_pre + (size_t)(e - 16) * 4096)
                                       : (w_post + (size_t)(e - 20) * 4096);
            const float4* wr4 = (const float4*)wr;
            #pragma unroll
            for (int q = 0; q < 4; ++q) {
                float4 wv = wr4[q * 256 + tid];
                wg[r][q] = make_float4(wv.x * g[q].x, wv.y * g[q].y,
                                       wv.z * g[q].z, wv.w * g[q].w);
            }
        }
        float acc[CHUNK][TOK_PER_BLK];
        #pragma unroll
        for (int m = 0; m < TOK_PER_BLK; ++m) {
            #pragma unroll
            for (int r = 0; r < CHUNK; ++r) {
                float a = 0.f;
                #pragma unroll
                for (int q = 0; q < 4; ++q)
                    a += wg[r][q].x * p[m][q].x + wg[r][q].y * p[m][q].y
                       + wg[r][q].z * p[m][q].z + wg[r][q].w * p[m][q].w;
                acc[r][m] = a;
            }
        }
        // 2-step butterfly -> 16 partials per wave -> LDS
        #pragma unroll
        for (int r = 0; r < CHUNK; ++r) {
            #pragma unroll
            for (int m = 0; m < TOK_PER_BLK; ++m) {
                float a = acc[r][m];
                a += __shfl_xor(a, 16, 64);
                a += __shfl_xor(a, 32, 64);
                if (lane < 16)
                    sh_part[(c * CHUNK + r) * TOK_PER_BLK + m][wave * 16 + lane] = a;
            }
        }
    }
    __syncthreads();

    // ---------------- Reduce: parallel column sums ----------------
    if (tid < NROWS * TOK_PER_BLK) {           // 96 threads: one (row,token) each
        const int e = tid >> 2, m = tid & 3;
        const float4* src = (const float4*)&sh_part[e * TOK_PER_BLK + m][0];
        float4 s4 = src[0];
        #pragma unroll
        for (int j = 1; j < 16; ++j) {
            float4 v = src[j];
            s4.x += v.x; s4.y += v.y; s4.z += v.z; s4.w += v.w;
        }
        sh_raw[m][e] = s4.x + s4.y + s4.z + s4.w;
    } else if (tid < NROWS * TOK_PER_BLK + TOK_PER_BLK) {
        const int m = tid - NROWS * TOK_PER_BLK;
        const float4* src = (const float4*)&sh_ssqp[m][0];
        float4 s4 = src[0];
        #pragma unroll
        for (int j = 1; j < 16; ++j) {
            float4 v = src[j];
            s4.x += v.x; s4.y += v.y; s4.z += v.z; s4.w += v.w;
        }
        sh_ssq[m] = s4.x + s4.y + s4.z + s4.w;
    }
    __syncthreads();

    // ---------------- Phase 3: sinkhorn + gates (one wave per token) --------
    {
        const int m   = wave;
        const int idx = lane & 15;     // (i,j): i = idx>>2, j = idx&3
        const int jj  = idx & 3;

        float ss    = sh_ssq[m];
        float scale = 64.0f / fmaxf(sqrtf(ss), 1e-12f);

        const float a_res  = p_alpha_res[0];
        const float a_pre  = p_alpha_pre[0];
        const float a_post = p_alpha_post[0];

        float Z = (beta_res[idx] + a_res * scale * sh_raw[m][idx]) * TAU_INV;
        float u = 0.f, v = 0.f;
        #pragma unroll 1
        for (int it = 0; it < 10; ++it) {
            float t  = Z + v;
            float mx = t;
            mx = fmaxf(mx, __shfl_xor(mx, 1, 64));
            mx = fmaxf(mx, __shfl_xor(mx, 2, 64));
            float sm = __expf(t - mx);
            sm += __shfl_xor(sm, 1, 64);
            sm += __shfl_xor(sm, 2, 64);
            u = -(mx + __logf(sm));
            t  = Z + u;
            mx = t;
            mx = fmaxf(mx, __shfl_xor(mx, 4, 64));
            mx = fmaxf(mx, __shfl_xor(mx, 8, 64));
            sm = __expf(t - mx);
            sm += __shfl_xor(sm, 4, 64);
            sm += __shfl_xor(sm, 8, 64);
            v = -(mx + __logf(sm));
        }
        float P = __expf(Z + u + v);
        if (lane < 16) sh_H[m][idx] = P;

        float lpre = beta_pre[jj] + a_pre * scale * sh_raw[m][16 + jj];
        float mxp = lpre;
        mxp = fmaxf(mxp, __shfl_xor(mxp, 1, 64));
        mxp = fmaxf(mxp, __shfl_xor(mxp, 2, 64));
        float ep = __expf(lpre - mxp);
        float sp = ep;
        sp += __shfl_xor(sp, 1, 64);
        sp += __shfl_xor(sp, 2, 64);
        float hpre = ep / sp;
        float lpost = beta_post[jj] + a_post * scale * sh_raw[m][20 + jj];
        float hpost = 2.0f / (1.0f + __expf(-lpost));
        if (lane < 4) { sh_H[m][16 + jj] = hpre; sh_H[m][20 + jj] = hpost; }
    }
    __syncthreads();

    // ---------------- Phase 4: remix + branch, store (FULLY UNROLLED: p[][]
    // must be indexed by compile-time constants or it spills to scratch) -----
    #pragma unroll
    for (int m = 0; m < TOK_PER_BLK; ++m) {
        float Hr[16], Hp[4], Ho[4];
        #pragma unroll
        for (int k = 0; k < 16; ++k) Hr[k] = sh_H[m][k];
        #pragma unroll
        for (int s = 0; s < 4; ++s) { Hp[s] = sh_H[m][16 + s]; Ho[s] = sh_H[m][20 + s]; }

        float4 br;
        br.x = Hp[0]*p[m][0].x + Hp[1]*p[m][1].x + Hp[2]*p[m][2].x + Hp[3]*p[m][3].x;
        br.y = Hp[0]*p[m][0].y + Hp[1]*p[m][1].y + Hp[2]*p[m][2].y + Hp[3]*p[m][3].y;
        br.z = Hp[0]*p[m][0].z + Hp[1]*p[m][1].z + Hp[2]*p[m][2].z + Hp[3]*p[m][3].z;
        br.w = Hp[0]*p[m][0].w + Hp[1]*p[m][1].w + Hp[2]*p[m][2].w + Hp[3]*p[m][3].w;

        float4* op = (float4*)out + (tok0 + m) * 1024;
        #pragma unroll
        for (int i = 0; i < 4; ++i) {
            float4 o;
            o.x = Hr[i*4+0]*p[m][0].x + Hr[i*4+1]*p[m][1].x + Hr[i*4+2]*p[m][2].x + Hr[i*4+3]*p[m][3].x + Ho[i]*br.x;
            o.y = Hr[i*4+0]*p[m][0].y + Hr[i*4+1]*p[m][1].y + Hr[i*4+2]*p[m][2].y + Hr[i*4+3]*p[m][3].y + Ho[i]*br.y;
            o.z = Hr[i*4+0]*p[m][0].z + Hr[i*4+1]*p[m][1].z + Hr[i*4+2]*p[m][2].z + Hr[i*4+3]*p[m][3].z + Ho[i]*br.z;
            o.w = Hr[i*4+0]*p[m][0].w + Hr[i*4+1]*p[m][1].w + Hr[i*4+2]*p[m][2].w + Hr[i*4+3]*p[m][3].w + Ho[i]*br.w;
            op[i * 256 + tid] = o;
        }
    }
}

extern "C" void kernel_launch(void* const* d_in, const int* in_sizes, int n_in,
                              void* d_out, int out_size, void* d_ws, size_t ws_size,
                              hipStream_t stream) {
    const float* resid      = (const float*)d_in[0];
    const float* gamma      = (const float*)d_in[1];
    const float* w_res      = (const float*)d_in[2];
    const float* w_pre      = (const float*)d_in[3];
    const float* w_post     = (const float*)d_in[4];
    const float* beta_res   = (const float*)d_in[5];
    const float* beta_pre   = (const float*)d_in[6];
    const float* beta_post  = (const float*)d_in[7];
    const float* alpha_res  = (const float*)d_in[8];
    const float* alpha_pre  = (const float*)d_in[9];
    const float* alpha_post = (const float*)d_in[10];
    float* out = (float*)d_out;

    const int ntok = in_sizes[0] / 4096;          // B*T = 8192
    const int grid = ntok / TOK_PER_BLK;          // 2048

    hc_fused<<<grid, THREADS, 0, stream>>>(resid, gamma, w_res, w_pre, w_post,
                                           beta_res, beta_pre, beta_post,
                                           alpha_res, alpha_pre, alpha_post, out);
}

// Round 4
// 307.886 us; speedup vs baseline: 1.1839x; 1.0002x over previous
//
#include <hip/hip_runtime.h>
#include <hip/hip_bf16.h>
#include <math.h>

#define TOK_PER_BLK 4
#define THREADS 256
#define CHUNK 2      // weight rows per chunk buffer
#define NCHUNK 12    // 24 rows total
#define NROWS 24
#define PCOL 68      // 64 partials + pad
#define TAU_INV 20.0f   // 1/0.05

// One block = 4 tokens, 256 threads. Token = 4096 floats (S=4 streams x D=1024).
// Thread tid holds float4 (q*256+tid) of each token in REGISTERS (q = stream).
// NOTE: every loop touching p[][] must be fully unrolled (compile-time indices)
// or the array spills to scratch — R2 showed +131MB WRITE_SIZE from exactly that.
// Phase 2 is software-pipelined: weight chunk c+1 prefetches into the alternate
// register buffer while chunk c computes (R3 was chunk-serialized -> L2 latency
// exposed; VALUBusy 35%).
__global__ __launch_bounds__(THREADS, 3)
void hc_fused(const float* __restrict__ resid,
              const float* __restrict__ gamma,
              const float* __restrict__ w_res,
              const float* __restrict__ w_pre,
              const float* __restrict__ w_post,
              const float* __restrict__ beta_res,
              const float* __restrict__ beta_pre,
              const float* __restrict__ beta_post,
              const float* __restrict__ p_alpha_res,
              const float* __restrict__ p_alpha_pre,
              const float* __restrict__ p_alpha_post,
              float* __restrict__ out)
{
    __shared__ float sh_part[NROWS * TOK_PER_BLK][PCOL];  // 26 KB dot partials
    __shared__ float sh_ssqp[TOK_PER_BLK][PCOL];          // sumsq partials
    __shared__ float sh_raw[TOK_PER_BLK][NROWS];
    __shared__ float sh_ssq[TOK_PER_BLK];
    __shared__ float sh_H[TOK_PER_BLK][NROWS];  // [0..15]=H_res, [16..19]=H_pre, [20..23]=H_post

    const int tid  = threadIdx.x;
    const int wave = tid >> 6;
    const int lane = tid & 63;
    const long tok0 = (long)blockIdx.x * TOK_PER_BLK;

    // ---------------- Phase 1: global -> registers + sumsq ----------------
    const float4* hp = (const float4*)resid + tok0 * 1024;
    float4 p[TOK_PER_BLK][4];
    #pragma unroll
    for (int m = 0; m < TOK_PER_BLK; ++m) {
        #pragma unroll
        for (int q = 0; q < 4; ++q)
            p[m][q] = hp[m * 1024 + q * 256 + tid];
    }
    #pragma unroll
    for (int m = 0; m < TOK_PER_BLK; ++m) {
        float s = 0.f;
        #pragma unroll
        for (int q = 0; q < 4; ++q) {
            float4 v = p[m][q];
            s += v.x * v.x + v.y * v.y + v.z * v.z + v.w * v.w;
        }
        s += __shfl_xor(s, 16, 64);
        s += __shfl_xor(s, 32, 64);
        if (lane < 16) sh_ssqp[m][wave * 16 + lane] = s;
    }

    // gamma+1 in registers
    float4 g[4];
    {
        const float4* gp = (const float4*)gamma;
        #pragma unroll
        for (int q = 0; q < 4; ++q) {
            float4 gv = gp[q * 256 + tid];
            g[q] = make_float4(gv.x + 1.f, gv.y + 1.f, gv.z + 1.f, gv.w + 1.f);
        }
    }

    // ---------------- Phase 2: 24 dot products, double-buffered -------------
    // dot(w, x*(g+1)) = dot(w*(g+1), x): fold gamma into weights at use.
    auto load_chunk = [&](int c, float4 (&w)[CHUNK][4]) {
        #pragma unroll
        for (int r = 0; r < CHUNK; ++r) {
            const int e = c * CHUNK + r;
            const float* wr = (e < 16) ? (w_res + (size_t)e * 4096)
                            : (e < 20) ? (w_pre + (size_t)(e - 16) * 4096)
                                       : (w_post + (size_t)(e - 20) * 4096);
            const float4* wr4 = (const float4*)wr;
            #pragma unroll
            for (int q = 0; q < 4; ++q) w[r][q] = wr4[q * 256 + tid];
        }
    };
    auto compute_chunk = [&](int c, const float4 (&w)[CHUNK][4]) {
        #pragma unroll
        for (int r = 0; r < CHUNK; ++r) {
            float4 wg[4];
            #pragma unroll
            for (int q = 0; q < 4; ++q)
                wg[q] = make_float4(w[r][q].x * g[q].x, w[r][q].y * g[q].y,
                                    w[r][q].z * g[q].z, w[r][q].w * g[q].w);
            #pragma unroll
            for (int m = 0; m < TOK_PER_BLK; ++m) {
                float a = 0.f;
                #pragma unroll
                for (int q = 0; q < 4; ++q)
                    a += wg[q].x * p[m][q].x + wg[q].y * p[m][q].y
                       + wg[q].z * p[m][q].z + wg[q].w * p[m][q].w;
                a += __shfl_xor(a, 16, 64);
                a += __shfl_xor(a, 32, 64);
                if (lane < 16)
                    sh_part[(c * CHUNK + r) * TOK_PER_BLK + m][wave * 16 + lane] = a;
            }
        }
    };

    float4 wA[CHUNK][4], wB[CHUNK][4];
    load_chunk(0, wA);
    #pragma unroll 1
    for (int cc = 0; cc < NCHUNK / 2; ++cc) {
        load_chunk(2 * cc + 1, wB);
        compute_chunk(2 * cc, wA);
        if (cc + 1 < NCHUNK / 2) load_chunk(2 * cc + 2, wA);
        compute_chunk(2 * cc + 1, wB);
    }
    __syncthreads();

    // ---------------- Reduce: parallel column sums ----------------
    if (tid < NROWS * TOK_PER_BLK) {           // 96 threads: one (row,token) each
        const int e = tid >> 2, m = tid & 3;
        const float4* src = (const float4*)&sh_part[e * TOK_PER_BLK + m][0];
        float4 s4 = src[0];
        #pragma unroll
        for (int j = 1; j < 16; ++j) {
            float4 v = src[j];
            s4.x += v.x; s4.y += v.y; s4.z += v.z; s4.w += v.w;
        }
        sh_raw[m][e] = s4.x + s4.y + s4.z + s4.w;
    } else if (tid < NROWS * TOK_PER_BLK + TOK_PER_BLK) {
        const int m = tid - NROWS * TOK_PER_BLK;
        const float4* src = (const float4*)&sh_ssqp[m][0];
        float4 s4 = src[0];
        #pragma unroll
        for (int j = 1; j < 16; ++j) {
            float4 v = src[j];
            s4.x += v.x; s4.y += v.y; s4.z += v.z; s4.w += v.w;
        }
        sh_ssq[m] = s4.x + s4.y + s4.z + s4.w;
    }
    __syncthreads();

    // ---------------- Phase 3: sinkhorn + gates (one wave per token) --------
    {
        const int m   = wave;
        const int idx = lane & 15;     // (i,j): i = idx>>2, j = idx&3
        const int jj  = idx & 3;

        float ss    = sh_ssq[m];
        float scale = 64.0f / fmaxf(sqrtf(ss), 1e-12f);

        const float a_res  = p_alpha_res[0];
        const float a_pre  = p_alpha_pre[0];
        const float a_post = p_alpha_post[0];

        float Z = (beta_res[idx] + a_res * scale * sh_raw[m][idx]) * TAU_INV;
        float u = 0.f, v = 0.f;
        #pragma unroll 1
        for (int it = 0; it < 10; ++it) {
            float t  = Z + v;
            float mx = t;
            mx = fmaxf(mx, __shfl_xor(mx, 1, 64));
            mx = fmaxf(mx, __shfl_xor(mx, 2, 64));
            float sm = __expf(t - mx);
            sm += __shfl_xor(sm, 1, 64);
            sm += __shfl_xor(sm, 2, 64);
            u = -(mx + __logf(sm));
            t  = Z + u;
            mx = t;
            mx = fmaxf(mx, __shfl_xor(mx, 4, 64));
            mx = fmaxf(mx, __shfl_xor(mx, 8, 64));
            sm = __expf(t - mx);
            sm += __shfl_xor(sm, 4, 64);
            sm += __shfl_xor(sm, 8, 64);
            v = -(mx + __logf(sm));
        }
        float P = __expf(Z + u + v);
        if (lane < 16) sh_H[m][idx] = P;

        float lpre = beta_pre[jj] + a_pre * scale * sh_raw[m][16 + jj];
        float mxp = lpre;
        mxp = fmaxf(mxp, __shfl_xor(mxp, 1, 64));
        mxp = fmaxf(mxp, __shfl_xor(mxp, 2, 64));
        float ep = __expf(lpre - mxp);
        float sp = ep;
        sp += __shfl_xor(sp, 1, 64);
        sp += __shfl_xor(sp, 2, 64);
        float hpre = ep / sp;
        float lpost = beta_post[jj] + a_post * scale * sh_raw[m][20 + jj];
        float hpost = 2.0f / (1.0f + __expf(-lpost));
        if (lane < 4) { sh_H[m][16 + jj] = hpre; sh_H[m][20 + jj] = hpost; }
    }
    __syncthreads();

    // ---------------- Phase 4: remix + branch, store (FULLY UNROLLED) -------
    #pragma unroll
    for (int m = 0; m < TOK_PER_BLK; ++m) {
        float Hr[16], Hp[4], Ho[4];
        #pragma unroll
        for (int k = 0; k < 16; ++k) Hr[k] = sh_H[m][k];
        #pragma unroll
        for (int s = 0; s < 4; ++s) { Hp[s] = sh_H[m][16 + s]; Ho[s] = sh_H[m][20 + s]; }

        float4 br;
        br.x = Hp[0]*p[m][0].x + Hp[1]*p[m][1].x + Hp[2]*p[m][2].x + Hp[3]*p[m][3].x;
        br.y = Hp[0]*p[m][0].y + Hp[1]*p[m][1].y + Hp[2]*p[m][2].y + Hp[3]*p[m][3].y;
        br.z = Hp[0]*p[m][0].z + Hp[1]*p[m][1].z + Hp[2]*p[m][2].z + Hp[3]*p[m][3].z;
        br.w = Hp[0]*p[m][0].w + Hp[1]*p[m][1].w + Hp[2]*p[m][2].w + Hp[3]*p[m][3].w;

        float4* op = (float4*)out + (tok0 + m) * 1024;
        #pragma unroll
        for (int i = 0; i < 4; ++i) {
            float4 o;
            o.x = Hr[i*4+0]*p[m][0].x + Hr[i*4+1]*p[m][1].x + Hr[i*4+2]*p[m][2].x + Hr[i*4+3]*p[m][3].x + Ho[i]*br.x;
            o.y = Hr[i*4+0]*p[m][0].y + Hr[i*4+1]*p[m][1].y + Hr[i*4+2]*p[m][2].y + Hr[i*4+3]*p[m][3].y + Ho[i]*br.y;
            o.z = Hr[i*4+0]*p[m][0].z + Hr[i*4+1]*p[m][1].z + Hr[i*4+2]*p[m][2].z + Hr[i*4+3]*p[m][3].z + Ho[i]*br.z;
            o.w = Hr[i*4+0]*p[m][0].w + Hr[i*4+1]*p[m][1].w + Hr[i*4+2]*p[m][2].w + Hr[i*4+3]*p[m][3].w + Ho[i]*br.w;
            op[i * 256 + tid] = o;
        }
    }
}

extern "C" void kernel_launch(void* const* d_in, const int* in_sizes, int n_in,
                              void* d_out, int out_size, void* d_ws, size_t ws_size,
                              hipStream_t stream) {
    const float* resid      = (const float*)d_in[0];
    const float* gamma      = (const float*)d_in[1];
    const float* w_res      = (const float*)d_in[2];
    const float* w_pre      = (const float*)d_in[3];
    const float* w_post     = (const float*)d_in[4];
    const float* beta_res   = (const float*)d_in[5];
    const float* beta_pre   = (const float*)d_in[6];
    const float* beta_post  = (const float*)d_in[7];
    const float* alpha_res  = (const float*)d_in[8];
    const float* alpha_pre  = (const float*)d_in[9];
    const float* alpha_post = (const float*)d_in[10];
    float* out = (float*)d_out;

    const int ntok = in_sizes[0] / 4096;          // B*T = 8192
    const int grid = ntok / TOK_PER_BLK;          // 2048

    hc_fused<<<grid, THREADS, 0, stream>>>(resid, gamma, w_res, w_pre, w_post,
                                           beta_res, beta_pre, beta_post,
                                           alpha_res, alpha_pre, alpha_post, out);
}